// Round 5
// baseline (332.722 us; speedup 1.0000x reference)
//
#include <hip/hip_runtime.h>

typedef __attribute__((ext_vector_type(8))) short short8;
typedef __attribute__((ext_vector_type(4))) float f32x4;

#define N_TOK   16384
#define HDIM    1024
#define OUT_OFF 16777216   // 16384*1024
#define M1ROWS  26216      // 2*(2097+11011)
#define M2ROWS  22022      // 2*11011
#define L2ROW0  4194       // 2*2097

__device__ __forceinline__ unsigned short f2bf(float f) {
  unsigned int u = __float_as_uint(f);
  u += 0x7FFFu + ((u >> 16) & 1u);
  return (unsigned short)(u >> 16);
}

// gathered-row index -> (tensor, rank)
__device__ __forceinline__ void rowmap(int r, int& is_v, int& rank) {
  if (r < 2097)       { is_v = 0; rank = 3276 + r; }
  else if (r < 4194)  { is_v = 1; rank = 1179 + r; }
  else if (r < 15205) { is_v = 0; rank = 1179 + r; }
  else                { is_v = 1; rank = r - 9832; }
}

// ---- stable descending rank: count[i] = #{j : imp[j]>imp[i] or (== and j<i)} ----
__global__ __launch_bounds__(256) void rank_count(const float* __restrict__ imp,
                                                  int* __restrict__ counts) {
  __shared__ float sj[2048];
  const int i = blockIdx.x * 256 + threadIdx.x;
  const int jbase = blockIdx.y * 2048;
  const float vi = imp[i];
  for (int s = threadIdx.x; s < 2048; s += 256) sj[s] = imp[jbase + s];
  __syncthreads();
  int cnt = 0;
  #pragma unroll 8
  for (int s = 0; s < 2048; ++s) {
    float vj = sj[s];
    bool gt = vj > vi;
    bool eq = (vj == vi) && ((jbase + s) < i);
    cnt += (gt || eq) ? 1 : 0;
  }
  atomicAdd(&counts[i], cnt);
}

__global__ __launch_bounds__(256) void scatter_order(const int* __restrict__ counts,
                                                     int* __restrict__ order) {
  int i = blockIdx.x * 256 + threadIdx.x;
  order[counts[i]] = i;
}

// ---- weight convert: dst[N][K] bf16 (transposed, zero-padded) from src[Ksrc][Nsrc] f32 ----
__global__ __launch_bounds__(256) void wconv(unsigned short* __restrict__ dst,
                                             const float* __restrict__ src,
                                             int Nd, int Kd, int Nsrc, int Ksrc) {
  int idx = blockIdx.x * 256 + threadIdx.x;
  if (idx >= Nd * Kd) return;
  int n = idx / Kd, k = idx % Kd;
  float v = (n < Nsrc && k < Ksrc) ? src[k * Nsrc + n] : 0.f;
  dst[idx] = f2bf(v);
}

// ---- gather level>=1 rows into bf16 X ----
__global__ __launch_bounds__(256) void gather_rows(unsigned short* __restrict__ X,
                                                   const float* __restrict__ keys,
                                                   const float* __restrict__ values,
                                                   const int* __restrict__ order) {
  int r = blockIdx.x;
  int is_v, rank; rowmap(r, is_v, rank);
  int token = order[rank];
  const float* src = (is_v ? values : keys) + (size_t)token * HDIM;
  int c = threadIdx.x * 4;
  float4 f = *reinterpret_cast<const float4*>(src + c);
  ushort4 h;
  h.x = f2bf(f.x); h.y = f2bf(f.y); h.z = f2bf(f.z); h.w = f2bf(f.w);
  *reinterpret_cast<ushort4*>(X + (size_t)r * HDIM + c) = h;
}

// ---- level 0: exact f32 passthrough ----
__global__ __launch_bounds__(256) void copy_level0(float* __restrict__ out,
                                                   const float* __restrict__ keys,
                                                   const float* __restrict__ values,
                                                   const int* __restrict__ order) {
  int b = blockIdx.x;
  int is_v = b & 1, rank = b >> 1;
  int token = order[rank];
  const float* src = (is_v ? values : keys) + (size_t)token * HDIM;
  float* dst = out + (is_v ? OUT_OFF : 0) + (size_t)token * HDIM;
  int c = threadIdx.x * 4;
  *reinterpret_cast<float4*>(dst + c) = *reinterpret_cast<const float4*>(src + c);
}

#define GLDS16(g, l) __builtin_amdgcn_global_load_lds( \
    (const __attribute__((address_space(1))) void*)(g), \
    (__attribute__((address_space(3))) void*)(l), 16, 0, 0)

// ---- tiled bf16 GEMM: C = relu(A @ B + bias); B given transposed [N][K] ----
// m201-style schedule ported: BM=256 BN=128 BK=64, 8 waves (4Mx2N),
// 3-buffer LDS ring (144 KB), 2 phases per K-tile. Per phase:
//   {8x ds_read_b128 || issue 3 global_load_lds (tile t+2)} -> barrier ->
//   lgkmcnt(0) -> setprio(1) -> 16 MFMA -> setprio(0) -> barrier.
// vmcnt(6) only once per K-tile (6 loads of t+2 stay in flight; never 0
// mid-loop). LDS 3-bit XOR swizzle: slot = chunk ^ (row&7), realized via
// pre-swizzled per-lane GLOBAL source (gload_lds dest is linear) + same
// XOR on ds_read -> max 2-way bank conflict (free).
// XCD-bijective block swizzle: panel p pinned to XCD p%8.
// MODE 0: store bf16 to Cbf (ldc). MODE 1: scatter f32 to outf via rowmap/order.
template<int MODE>
__global__ __launch_bounds__(512, 2) void gemm_bias_relu(
    const unsigned short* __restrict__ A, int M, int K,
    const unsigned short* __restrict__ Bt, int N,
    const float* __restrict__ bias, int Nbias,
    unsigned short* __restrict__ Cbf, int ldc,
    float* __restrict__ outf, const int* __restrict__ order,
    int NP, int NC) {
  // per buffer: A 256x64 (16384 shorts) + B 128x64 (8192 shorts) = 48 KB
  __shared__ __align__(16) unsigned short S[3][24576];
  const int bid = blockIdx.x;
  const int r8 = bid & 7, rest = bid >> 3;
  const int c8 = rest % NC, q8 = rest / NC;
  const int p8 = q8 * 8 + r8;
  if (p8 >= NP) return;
  const int row0 = p8 * 256, col0 = c8 * 128;

  const int tid = threadIdx.x;
  const int wave = tid >> 6, lane = tid & 63;

  // ---- staging geometry: per gload instr a wave writes 1 KB = 8 rows x 128 B
  // lane: row_in_seg = lane>>3, slot = lane&7; content chunk = slot ^ (row&7)
  const int srow = lane >> 3;                    // 0..7 == row&7
  const int schunk = ((lane & 7) ^ srow) << 3;   // source col offset (shorts)
  const unsigned short* apg[4]; int aoff[4];
  #pragma unroll
  for (int j = 0; j < 4; ++j) {                  // A: 32 segs of 8 rows
    int g = wave * 4 + j;
    int rr = row0 + g * 8 + srow; if (rr >= M) rr = 0;
    apg[j] = A + (size_t)rr * K + schunk;
    aoff[j] = g * 512;                           // shorts
  }
  const unsigned short* bpg[2]; int boff[2];
  #pragma unroll
  for (int j = 0; j < 2; ++j) {                  // B: 16 segs of 8 rows
    int g = wave * 2 + j;
    int rr = col0 + g * 8 + srow; if (rr >= N) rr = 0;
    bpg[j] = Bt + (size_t)rr * K + schunk;
    boff[j] = 16384 + g * 512;
  }

  // ---- fragment read geometry (wave outputs 64x64 at (wr, wc))
  const int wr = (wave >> 1) * 64, wc = (wave & 1) * 64;
  const int fr = lane & 15, lch = lane >> 4;     // frag row, k-chunk 0..3
  const int q0 = ((lch ^ (fr & 7)) << 3);        // kk=0 swizzled chunk (shorts)
  const int q1 = (((4 | lch) ^ (fr & 7)) << 3);  // kk=1

  f32x4 acc[4][4] = {};
  const int nt = K >> 6;

  // prologue: stage tiles 0,1
  #pragma unroll
  for (int j = 0; j < 4; ++j) GLDS16(apg[j], S[0] + aoff[j]);
  #pragma unroll
  for (int j = 0; j < 2; ++j) GLDS16(bpg[j], S[0] + boff[j]);
  #pragma unroll
  for (int j = 0; j < 4; ++j) GLDS16(apg[j] + 64, S[1] + aoff[j]);
  #pragma unroll
  for (int j = 0; j < 2; ++j) GLDS16(bpg[j] + 64, S[1] + boff[j]);
  asm volatile("s_waitcnt vmcnt(6)" ::: "memory");   // tile 0 landed
  __builtin_amdgcn_s_barrier();

  int bufc = 0;
  for (int t = 0; t < nt; ++t) {
    const unsigned short* as = S[bufc];
    const unsigned short* bs = S[bufc] + 16384;
    const bool pf = (t + 2 < nt);
    const int k2 = (t + 2) << 6;
    int nb = bufc + 2; if (nb >= 3) nb -= 3;
    short8 af[4], bf[4];
    // ======== phase 0 (kk = 0) ========
    #pragma unroll
    for (int m = 0; m < 4; ++m)
      af[m] = *reinterpret_cast<const short8*>(as + (wr + m * 16 + fr) * 64 + q0);
    #pragma unroll
    for (int n = 0; n < 4; ++n)
      bf[n] = *reinterpret_cast<const short8*>(bs + (wc + n * 16 + fr) * 64 + q0);
    if (pf) {
      GLDS16(apg[0] + k2, S[nb] + aoff[0]);
      GLDS16(apg[1] + k2, S[nb] + aoff[1]);
      GLDS16(bpg[0] + k2, S[nb] + boff[0]);
    }
    __builtin_amdgcn_s_barrier();
    asm volatile("s_waitcnt lgkmcnt(0)" ::: "memory");
    __builtin_amdgcn_sched_barrier(0);
    __builtin_amdgcn_s_setprio(1);
    #pragma unroll
    for (int m = 0; m < 4; ++m)
      #pragma unroll
      for (int n = 0; n < 4; ++n)
        acc[m][n] = __builtin_amdgcn_mfma_f32_16x16x32_bf16(af[m], bf[n], acc[m][n], 0, 0, 0);
    __builtin_amdgcn_s_setprio(0);
    __builtin_amdgcn_s_barrier();
    // ======== phase 1 (kk = 1) ========
    #pragma unroll
    for (int m = 0; m < 4; ++m)
      af[m] = *reinterpret_cast<const short8*>(as + (wr + m * 16 + fr) * 64 + q1);
    #pragma unroll
    for (int n = 0; n < 4; ++n)
      bf[n] = *reinterpret_cast<const short8*>(bs + (wc + n * 16 + fr) * 64 + q1);
    if (pf) {
      GLDS16(apg[2] + k2, S[nb] + aoff[2]);
      GLDS16(apg[3] + k2, S[nb] + aoff[3]);
      GLDS16(bpg[1] + k2, S[nb] + boff[1]);
    }
    __builtin_amdgcn_s_barrier();
    asm volatile("s_waitcnt lgkmcnt(0)" ::: "memory");
    __builtin_amdgcn_sched_barrier(0);
    __builtin_amdgcn_s_setprio(1);
    #pragma unroll
    for (int m = 0; m < 4; ++m)
      #pragma unroll
      for (int n = 0; n < 4; ++n)
        acc[m][n] = __builtin_amdgcn_mfma_f32_16x16x32_bf16(af[m], bf[n], acc[m][n], 0, 0, 0);
    __builtin_amdgcn_s_setprio(0);
    if (pf) asm volatile("s_waitcnt vmcnt(6)" ::: "memory");  // t+1 landed, t+2 in flight
    else    asm volatile("s_waitcnt vmcnt(0)" ::: "memory");
    __builtin_amdgcn_s_barrier();
    bufc = (bufc == 2) ? 0 : bufc + 1;
  }

  const int orow = lch * 4;
  const int ocol = fr;
  #pragma unroll
  for (int m = 0; m < 4; ++m) {
    #pragma unroll
    for (int n = 0; n < 4; ++n) {
      #pragma unroll
      for (int j = 0; j < 4; ++j) {
        int r = row0 + wr + m * 16 + orow + j;
        int c = col0 + wc + n * 16 + ocol;
        if (r < M && c < N) {
          float v = acc[m][n][j] + (c < Nbias ? bias[c] : 0.f);
          v = fmaxf(v, 0.f);
          if (MODE == 0) {
            Cbf[(size_t)r * ldc + c] = f2bf(v);
          } else {
            int iv, rk; rowmap(r, iv, rk);
            int token = order[rk];
            outf[(size_t)(iv ? OUT_OFF : 0) + (size_t)token * HDIM + c] = v;
          }
        }
      }
    }
  }
}

static inline int swz_grid(int NP, int NC) { return 8 * NC * ((NP + 7) / 8); }

extern "C" void kernel_launch(void* const* d_in, const int* in_sizes, int n_in,
                              void* d_out, int out_size, void* d_ws, size_t ws_size,
                              hipStream_t stream) {
  const float* keys   = (const float*)d_in[0];
  const float* values = (const float*)d_in[1];
  const float* imp    = (const float*)d_in[2];
  const float* We0    = (const float*)d_in[3];
  const float* be0    = (const float*)d_in[4];
  const float* We1    = (const float*)d_in[5];
  const float* be1    = (const float*)d_in[6];
  const float* Wd0    = (const float*)d_in[7];
  const float* bd0    = (const float*)d_in[8];
  const float* Wd1    = (const float*)d_in[9];
  const float* bd1    = (const float*)d_in[10];

  char* ws = (char*)d_ws;
  int* counts           = (int*)(ws);                       // 64 KB
  int* order            = (int*)(ws + 65536);               // 64 KB
  unsigned short* We0T  = (unsigned short*)(ws + 131072);   // [512][1024]
  unsigned short* We1T  = (unsigned short*)(ws + 1179648);  // [224][512]
  unsigned short* Wd1T  = (unsigned short*)(ws + 1409024);  // [512][256] (K padded)
  unsigned short* Wd0T  = (unsigned short*)(ws + 1671168);  // [1024][512]
  unsigned short* Y     = (unsigned short*)(ws + 2719744);  // [26216][512]
  unsigned short* Z     = (unsigned short*)(ws + 29564928); // [22022][256] (padded)
  // X (gathered bf16 inputs) lives in d_out; consumed by GEMM1 before any d_out write.
  unsigned short* X = (unsigned short*)d_out;
  float* outf = (float*)d_out;

  hipMemsetAsync(counts, 0, 65536, stream);
  hipMemsetAsync(Z, 0, (size_t)22022 * 256 * 2, stream);  // zero K-padding cols
  rank_count<<<dim3(64, 8), 256, 0, stream>>>(imp, counts);
  scatter_order<<<64, 256, 0, stream>>>(counts, order);

  wconv<<<2048, 256, 0, stream>>>(We0T, We0, 512, 1024, 512, 1024);
  wconv<<<448,  256, 0, stream>>>(We1T, We1, 224, 512, 204, 512);
  wconv<<<512,  256, 0, stream>>>(Wd1T, Wd1, 512, 256, 512, 204);
  wconv<<<2048, 256, 0, stream>>>(Wd0T, Wd0, 1024, 512, 1024, 512);

  gather_rows<<<M1ROWS, 256, 0, stream>>>(X, keys, values, order);

  // GEMM1: Y = relu(X @ We0 + be0)   [26216 x 1024] x [1024 x 512]
  gemm_bias_relu<0><<<swz_grid(103, 4), 512, 0, stream>>>(
      X, M1ROWS, 1024, We0T, 512, be0, 512, Y, 512, nullptr, nullptr, 103, 4);

  // level-0 exact copies (after X consumed)
  copy_level0<<<6552, 256, 0, stream>>>(outf, keys, values, order);

  // GEMM2a: Z = relu(Y_l2 @ We1 + be1)   [22022 x 512] x [512 x 224(pad)], ldc=256
  gemm_bias_relu<0><<<swz_grid(87, 2), 512, 0, stream>>>(
      Y + (size_t)L2ROW0 * 512, M2ROWS, 512, We1T, 224, be1, 204, Z, 256,
      nullptr, nullptr, 87, 2);

  // GEMM2b: Y_l2 = relu(Z @ Wd1 + bd1)   [22022 x 256pad] x [256 x 512]
  gemm_bias_relu<0><<<swz_grid(87, 4), 512, 0, stream>>>(
      Z, M2ROWS, 256, Wd1T, 512, bd1, 512, Y + (size_t)L2ROW0 * 512, 512,
      nullptr, nullptr, 87, 4);

  // GEMM3: out = relu(Y @ Wd0 + bd0), scattered f32  [26216 x 512] x [512 x 1024]
  gemm_bias_relu<1><<<swz_grid(103, 8), 512, 0, stream>>>(
      Y, M1ROWS, 512, Wd0T, 1024, bd0, 1024, nullptr, 0, outf, order, 103, 8);
}

// Round 6
// 272.123 us; speedup vs baseline: 1.2227x; 1.2227x over previous
//
#include <hip/hip_runtime.h>

typedef __attribute__((ext_vector_type(8))) short short8;
typedef __attribute__((ext_vector_type(4))) float f32x4;

#define N_TOK   16384
#define HDIM    1024
#define OUT_OFF 16777216   // 16384*1024
#define M1ROWS  26216      // 2*(2097+11011)
#define M2ROWS  22022      // 2*11011
#define L2ROW0  4194       // 2*2097

__device__ __forceinline__ unsigned short f2bf(float f) {
  unsigned int u = __float_as_uint(f);
  u += 0x7FFFu + ((u >> 16) & 1u);
  return (unsigned short)(u >> 16);
}

// gathered-row index -> (tensor, rank)
__device__ __forceinline__ void rowmap(int r, int& is_v, int& rank) {
  if (r < 2097)       { is_v = 0; rank = 3276 + r; }
  else if (r < 4194)  { is_v = 1; rank = 1179 + r; }
  else if (r < 15205) { is_v = 0; rank = 1179 + r; }
  else                { is_v = 1; rank = r - 9832; }
}

// ---- stable descending rank: count[i] = #{j : imp[j]>imp[i] or (== and j<i)} ----
__global__ __launch_bounds__(256) void rank_count(const float* __restrict__ imp,
                                                  int* __restrict__ counts) {
  __shared__ float sj[2048];
  const int i = blockIdx.x * 256 + threadIdx.x;
  const int jbase = blockIdx.y * 2048;
  const float vi = imp[i];
  for (int s = threadIdx.x; s < 2048; s += 256) sj[s] = imp[jbase + s];
  __syncthreads();
  int cnt = 0;
  #pragma unroll 8
  for (int s = 0; s < 2048; ++s) {
    float vj = sj[s];
    bool gt = vj > vi;
    bool eq = (vj == vi) && ((jbase + s) < i);
    cnt += (gt || eq) ? 1 : 0;
  }
  atomicAdd(&counts[i], cnt);
}

__global__ __launch_bounds__(256) void scatter_order(const int* __restrict__ counts,
                                                     int* __restrict__ order) {
  int i = blockIdx.x * 256 + threadIdx.x;
  order[counts[i]] = i;
}

// ---- weight convert: dst[N][K] bf16 (transposed, zero-padded) from src[Ksrc][Nsrc] f32 ----
__global__ __launch_bounds__(256) void wconv(unsigned short* __restrict__ dst,
                                             const float* __restrict__ src,
                                             int Nd, int Kd, int Nsrc, int Ksrc) {
  int idx = blockIdx.x * 256 + threadIdx.x;
  if (idx >= Nd * Kd) return;
  int n = idx / Kd, k = idx % Kd;
  float v = (n < Nsrc && k < Ksrc) ? src[k * Nsrc + n] : 0.f;
  dst[idx] = f2bf(v);
}

// ---- gather level>=1 rows into bf16 X (in d_ws) ----
__global__ __launch_bounds__(256) void gather_rows(unsigned short* __restrict__ X,
                                                   const float* __restrict__ keys,
                                                   const float* __restrict__ values,
                                                   const int* __restrict__ order) {
  int r = blockIdx.x;
  int is_v, rank; rowmap(r, is_v, rank);
  int token = order[rank];
  const float* src = (is_v ? values : keys) + (size_t)token * HDIM;
  int c = threadIdx.x * 4;
  float4 f = *reinterpret_cast<const float4*>(src + c);
  ushort4 h;
  h.x = f2bf(f.x); h.y = f2bf(f.y); h.z = f2bf(f.z); h.w = f2bf(f.w);
  *reinterpret_cast<ushort4*>(X + (size_t)r * HDIM + c) = h;
}

// ---- level 0: exact f32 passthrough ----
__global__ __launch_bounds__(256) void copy_level0(float* __restrict__ out,
                                                   const float* __restrict__ keys,
                                                   const float* __restrict__ values,
                                                   const int* __restrict__ order) {
  int b = blockIdx.x;
  int is_v = b & 1, rank = b >> 1;
  int token = order[rank];
  const float* src = (is_v ? values : keys) + (size_t)token * HDIM;
  float* dst = out + (is_v ? OUT_OFF : 0) + (size_t)token * HDIM;
  int c = threadIdx.x * 4;
  *reinterpret_cast<float4*>(dst + c) = *reinterpret_cast<const float4*>(src + c);
}

#define GLDS16(g, l) __builtin_amdgcn_global_load_lds( \
    (const __attribute__((address_space(1))) void*)(g), \
    (__attribute__((address_space(3))) void*)(l), 16, 0, 0)

// ---- tiled bf16 GEMM: C = relu(A @ B + bias); B given transposed [N][K] ----
// 256x128 tile, 8 waves, BK=32, 3-buffer ring (72 KB LDS -> 2 blocks/CU),
// counted s_waitcnt vmcnt(3) (never 0 mid-loop), loads 2 tiles ahead.
// XOR-swizzled LDS (pre-swizzled global source + read-side XOR): conflict-free.
// XCD-bijective block swizzle: panel p pinned to XCD p%8.
// MODE 0: store bf16 to Cbf (ldc).
// MODE 1 (GEMM3 only; requires N == NC*128, Nbias == N): relu+bias into LDS
//   band [64][136] f32, then cooperative 512-B-granule scatter by token row.
template<int MODE>
__global__ __launch_bounds__(512) void gemm_bias_relu(
    const unsigned short* __restrict__ A, int M, int K,
    const unsigned short* __restrict__ Bt, int N,
    const float* __restrict__ bias, int Nbias,
    unsigned short* __restrict__ Cbf, int ldc,
    float* __restrict__ outf, const int* __restrict__ order,
    int NP, int NC) {
  __shared__ __align__(16) unsigned short S[3][12288];
  // XCD swizzle: bid = r + 8*(c + NC*q); panel p = 8q + r -> XCD = bid%8 = p%8
  const int bid = blockIdx.x;
  const int r8 = bid & 7;
  const int rest = bid >> 3;
  const int c8 = rest % NC;
  const int q8 = rest / NC;
  const int p8 = q8 * 8 + r8;
  if (p8 >= NP) return;
  const int row0 = p8 * 256, col0 = c8 * 128;

  const int tid = threadIdx.x;
  const int wave = tid >> 6, lane = tid & 63;
  const int lrow = lane >> 2;
  // source chunk for linear LDS slot (lane&3) of row (lane>>2):
  const int lk = (((lane & 3) ^ ((lane >> 3) & 3)) << 3);
  const int wr = (wave >> 1) * 64, wc = (wave & 1) * 64;

  // staging: 24 segments of 16 rows (A: segs 0..15, B: segs 16..23);
  // wave w handles segs 3w..3w+2 -> 3 global_load_lds per wave per tile
  const unsigned short* gp[3];
  int ldso[3];
  #pragma unroll
  for (int j = 0; j < 3; ++j) {
    const int g = wave * 3 + j;
    const bool isA = g < 16;
    int rr = isA ? (row0 + g * 16 + lrow) : (col0 + (g - 16) * 16 + lrow);
    const int lim = isA ? M : N;
    if (rr >= lim) rr = 0;
    gp[j] = (isA ? A : Bt) + (size_t)rr * K + lk;
    ldso[j] = g * 512;
  }

  f32x4 acc[4][4] = {};
  const int fr = lane & 15;
  // read-side swizzle: chunk q=(lane>>4) of row (…+fr) lives at slot q^((fr>>1)&3)
  const int qoff = (((lane >> 4) ^ ((fr >> 1) & 3)) << 3);

  const int nt = K >> 5;
  // prologue: stage tiles 0,1 into bufs 0,1 (6 outstanding loads per wave)
  #pragma unroll
  for (int j = 0; j < 3; ++j) GLDS16(gp[j], S[0] + ldso[j]);
  #pragma unroll
  for (int j = 0; j < 3; ++j) GLDS16(gp[j] + 32, S[1] + ldso[j]);

  int cur = 0;
  for (int t = 0; t < nt; ++t) {
    // own tile-t loads done (<=3 outstanding = tile t+1); never drain to 0 mid-loop
    if (t + 1 < nt) asm volatile("s_waitcnt vmcnt(3)" ::: "memory");
    else            asm volatile("s_waitcnt vmcnt(0)" ::: "memory");
    __builtin_amdgcn_s_barrier();          // all waves' tile-t loads landed
    __builtin_amdgcn_sched_barrier(0);
    const unsigned short* as = S[cur];
    const unsigned short* bs = S[cur] + 8192;
    short8 af[4], bfv[4];
    #pragma unroll
    for (int m = 0; m < 4; ++m)
      af[m] = *reinterpret_cast<const short8*>(as + (wr + m * 16 + fr) * 32 + qoff);
    #pragma unroll
    for (int n = 0; n < 4; ++n)
      bfv[n] = *reinterpret_cast<const short8*>(bs + (wc + n * 16 + fr) * 32 + qoff);
    if (t + 2 < nt) {                      // issue 2-ahead into the freed buffer
      const int k2 = (t + 2) << 5;
      int nb = cur + 2; if (nb >= 3) nb -= 3;
      #pragma unroll
      for (int j = 0; j < 3; ++j) GLDS16(gp[j] + k2, S[nb] + ldso[j]);
    }
    #pragma unroll
    for (int m = 0; m < 4; ++m)
      #pragma unroll
      for (int n = 0; n < 4; ++n)
        acc[m][n] = __builtin_amdgcn_mfma_f32_16x16x32_bf16(af[m], bfv[n], acc[m][n], 0, 0, 0);
    cur = (cur == 2) ? 0 : cur + 1;
  }

  const int orow = (lane >> 4) * 4;
  const int ocol = lane & 15;
  if (MODE == 0) {
    #pragma unroll
    for (int m = 0; m < 4; ++m) {
      #pragma unroll
      for (int n = 0; n < 4; ++n) {
        #pragma unroll
        for (int j = 0; j < 4; ++j) {
          int r = row0 + wr + m * 16 + orow + j;
          int c = col0 + wc + n * 16 + ocol;
          if (r < M && c < N) {
            float v = acc[m][n][j] + (c < Nbias ? bias[c] : 0.f);
            Cbf[(size_t)r * ldc + c] = f2bf(fmaxf(v, 0.f));
          }
        }
      }
    }
  } else {
    // LDS-staged scatter: 4 passes of 64-row bands; writes are 512 B/row-chunk.
    float* Cl = (float*)S;                 // [64][136] f32 = 34.8 KB (fits in S)
    #pragma unroll 1
    for (int p = 0; p < 4; ++p) {
      __builtin_amdgcn_s_barrier();        // band buffer free
      if ((wave >> 1) == p) {              // waves 2p, 2p+1 own this band
        #pragma unroll
        for (int m = 0; m < 4; ++m)
          #pragma unroll
          for (int n = 0; n < 4; ++n)
            #pragma unroll
            for (int j = 0; j < 4; ++j) {
              int rr = m * 16 + orow + j;          // 0..63
              int cc = wc + n * 16 + ocol;         // 0..127
              float v = acc[m][n][j] + bias[col0 + cc];
              Cl[rr * 136 + cc] = fmaxf(v, 0.f);
            }
      }
      __builtin_amdgcn_s_barrier();        // band staged
      #pragma unroll
      for (int u = 0; u < 4; ++u) {
        int unit = tid + u * 512;          // 64 rows x 32 chunks = 2048 units
        int rr = unit >> 5, ch = unit & 31;
        int r = row0 + p * 64 + rr;
        if (r < M) {
          int iv, rk; rowmap(r, iv, rk);
          int token = order[rk];
          f32x4 v = *reinterpret_cast<const f32x4*>(Cl + rr * 136 + ch * 4);
          *reinterpret_cast<f32x4*>(outf + (size_t)(iv ? OUT_OFF : 0) +
                                    (size_t)token * HDIM + col0 + ch * 4) = v;
        }
      }
    }
  }
}

static inline int swz_grid(int NP, int NC) { return 8 * NC * ((NP + 7) / 8); }

extern "C" void kernel_launch(void* const* d_in, const int* in_sizes, int n_in,
                              void* d_out, int out_size, void* d_ws, size_t ws_size,
                              hipStream_t stream) {
  const float* keys   = (const float*)d_in[0];
  const float* values = (const float*)d_in[1];
  const float* imp    = (const float*)d_in[2];
  const float* We0    = (const float*)d_in[3];
  const float* be0    = (const float*)d_in[4];
  const float* We1    = (const float*)d_in[5];
  const float* be1    = (const float*)d_in[6];
  const float* Wd0    = (const float*)d_in[7];
  const float* bd0    = (const float*)d_in[8];
  const float* Wd1    = (const float*)d_in[9];
  const float* bd1    = (const float*)d_in[10];

  char* ws = (char*)d_ws;
  int* counts           = (int*)(ws);                       // 64 KB
  int* order            = (int*)(ws + 65536);               // 64 KB
  unsigned short* We0T  = (unsigned short*)(ws + 131072);   // [512][1024]
  unsigned short* We1T  = (unsigned short*)(ws + 1179648);  // [224][512]
  unsigned short* Wd1T  = (unsigned short*)(ws + 1409024);  // [512][224]
  unsigned short* Wd0T  = (unsigned short*)(ws + 1638400);  // [1024][512]
  unsigned short* Y     = (unsigned short*)(ws + 2686976);  // [26216][512]
  unsigned short* Z     = (unsigned short*)(ws + 29532160); // [22022][224]
  unsigned short* X     = (unsigned short*)(ws + 39398016); // [26216][1024]
  float* outf = (float*)d_out;

  hipMemsetAsync(counts, 0, 65536, stream);
  rank_count<<<dim3(64, 8), 256, 0, stream>>>(imp, counts);
  scatter_order<<<64, 256, 0, stream>>>(counts, order);

  wconv<<<2048, 256, 0, stream>>>(We0T, We0, 512, 1024, 512, 1024);
  wconv<<<448,  256, 0, stream>>>(We1T, We1, 224, 512, 204, 512);
  wconv<<<448,  256, 0, stream>>>(Wd1T, Wd1, 512, 224, 512, 204);
  wconv<<<2048, 256, 0, stream>>>(Wd0T, Wd0, 1024, 512, 1024, 512);

  gather_rows<<<M1ROWS, 256, 0, stream>>>(X, keys, values, order);
  copy_level0<<<6552, 256, 0, stream>>>(outf, keys, values, order);

  // GEMM1: Y = relu(X @ We0 + be0)   [26216 x 1024] x [1024 x 512]
  gemm_bias_relu<0><<<swz_grid(103, 4), 512, 0, stream>>>(
      X, M1ROWS, 1024, We0T, 512, be0, 512, Y, 512, nullptr, nullptr, 103, 4);

  // GEMM2a: Z = relu(Y_l2 @ We1 + be1)   [22022 x 512] x [512 x 224(pad)]
  gemm_bias_relu<0><<<swz_grid(87, 2), 512, 0, stream>>>(
      Y + (size_t)L2ROW0 * 512, M2ROWS, 512, We1T, 224, be1, 204, Z, 224,
      nullptr, nullptr, 87, 2);

  // GEMM2b: Y_l2 = relu(Z @ Wd1 + bd1)   [22022 x 224] x [224 x 512]
  gemm_bias_relu<0><<<swz_grid(87, 4), 512, 0, stream>>>(
      Z, M2ROWS, 224, Wd1T, 512, bd1, 512, Y + (size_t)L2ROW0 * 512, 512,
      nullptr, nullptr, 87, 4);

  // GEMM3: out = relu(Y @ Wd0 + bd0), LDS-staged 512B-granule scatter
  gemm_bias_relu<1><<<swz_grid(103, 8), 512, 0, stream>>>(
      Y, M1ROWS, 512, Wd0T, 1024, bd0, 1024, nullptr, 0, outf, order, 103, 8);
}